// Round 6
// baseline (230.064 us; speedup 1.0000x reference)
//
#include <hip/hip_runtime.h>
#include <math.h>

#define ZEPS  0.01f
#define ZMEAN 0.1307f
#define ZSIGMA 0.3081f

constexpr int D = 1024, H = 4096, O = 10;

using short8 = __attribute__((ext_vector_type(8))) short;
using f32x4  = __attribute__((ext_vector_type(4))) float;

__device__ inline unsigned short f2bf(float x) {  // RNE fp32 -> bf16 bits
    unsigned int u = __float_as_uint(x);
    u += 0x7FFFu + ((u >> 16) & 1u);
    return (unsigned short)(u >> 16);
}

// round-half-up fp32 pair -> packed bf16x2 (2 ops/elt; unbiased except exact ties)
__device__ inline unsigned int f2bf2_fast(float a, float b) {
    unsigned int ua = __float_as_uint(a) + 0x8000u;
    unsigned int ub = __float_as_uint(b) + 0x8000u;
    return (ua >> 16) | (ub & 0xFFFF0000u);
}

// async 16B/lane global->LDS (lds dest = base + lane*16, wave-uniform base)
__device__ inline void gl_lds16(const void* g, void* l) {
    __builtin_amdgcn_global_load_lds(
        (const __attribute__((address_space(1))) unsigned int*)g,
        (__attribute__((address_space(3))) unsigned int*)l, 16, 0, 0);
}

__device__ inline float zval(float xv) {  // normalized center
    float up = fminf(xv + ZEPS, 1.f);
    float lo = fmaxf(xv - ZEPS, 0.f);
    return (up + lo - ZMEAN) / ZSIGMA;
}
__device__ inline float zdia(float xv) {  // eps diagonal
    return fminf(xv + ZEPS, 1.f) / ZSIGMA;
}

// ---------------------------------------------------------------------------
__device__ inline void relu_params(float v, float r, float& vout, float& aout, float& tout) {
    float u = v + r, l = v - r;
    float denom = u - l;
    float slope = u / (denom == 0.f ? 1.f : denom);
    float term = (1.f - slope) * u * 0.5f;
    bool dead = (u <= 0.f);
    bool crossing = (u > 0.f) && (l < 0.f);
    vout = dead ? 0.f : (crossing ? (slope * v + term) : v);
    aout = dead ? 0.f : (crossing ? slope : 1.f);
    tout = (!dead && crossing) ? term : 0.f;
}

// ---------------------------------------------------------------------------
// wave-per-row: v1 = W1@values+b1 ; r1 = |W1| @ d ; ReLU-1 params
__global__ __launch_bounds__(256) void k_layer1(const float* __restrict__ W1, const float* __restrict__ b1,
                                                const float* __restrict__ x,
                                                float* __restrict__ v1p, float* __restrict__ a1,
                                                float* __restrict__ t1) {
    int wid = threadIdx.x >> 6, lane = threadIdx.x & 63;
    int i = blockIdx.x * 4 + wid;
    const float* row = W1 + (size_t)i * D;
    float sv = 0.f, sr = 0.f;
#pragma unroll
    for (int it = 0; it < 4; ++it) {
        int j = it * 256 + lane * 4;
        float4 w = *(const float4*)&row[j];
        float4 xx = *(const float4*)&x[j];
        sv += w.x * zval(xx.x) + w.y * zval(xx.y) + w.z * zval(xx.z) + w.w * zval(xx.w);
        sr += fabsf(w.x) * zdia(xx.x) + fabsf(w.y) * zdia(xx.y) +
              fabsf(w.z) * zdia(xx.z) + fabsf(w.w) * zdia(xx.w);
    }
#pragma unroll
    for (int m = 1; m <= 32; m <<= 1) {
        sv += __shfl_xor(sv, m, 64);
        sr += __shfl_xor(sr, m, 64);
    }
    if (lane == 0) {
        float vo, ao, to;
        relu_params(sv + b1[i], sr, vo, ao, to);
        v1p[i] = vo; a1[i] = ao; t1[i] = to;
    }
}

// W1sT[j][k] = bf16( a1[k] * W1[k][j] * d[j] )  — transposed, k-contiguous
__global__ __launch_bounds__(256) void k_scaleT(const float* __restrict__ W1, const float* __restrict__ a1,
                                                const float* __restrict__ x,
                                                unsigned short* __restrict__ W1sT) {
    __shared__ float tile[32][33];
    int j0 = blockIdx.x * 32, k0 = blockIdx.y * 32;
    int r = threadIdx.x >> 3;         // 0..31
    int c = (threadIdx.x & 7) * 4;    // 0,4,..,28
    float4 w = *(const float4*)&W1[(size_t)(k0 + r) * D + j0 + c];
    float4 xx = *(const float4*)&x[j0 + c];
    float a = a1[k0 + r];
    tile[r][c + 0] = a * w.x * zdia(xx.x);
    tile[r][c + 1] = a * w.y * zdia(xx.y);
    tile[r][c + 2] = a * w.z * zdia(xx.z);
    tile[r][c + 3] = a * w.w * zdia(xx.w);
    __syncthreads();
    ushort4 o;
    o.x = f2bf(tile[c + 0][r]);
    o.y = f2bf(tile[c + 1][r]);
    o.z = f2bf(tile[c + 2][r]);
    o.w = f2bf(tile[c + 3][r]);
    *(ushort4*)&W1sT[(size_t)(j0 + r) * H + k0 + c] = o;
}

// ---------------------------------------------------------------------------
// eps2 = bf16(W2) @ W1sT^T, split-K=2, XCD remap (b%8 -> XCD; z=u>>2).
// A staged from fp32 W2 with in-register bf16 cvt + swizzled ds_write_b128.
// v2/t2col partial dots computed from the fp32 A regs on k-steps (s&7)==xb,
// against v1p/t1 pre-staged to LDS; written race-free to vpart/tpart[z*8+xb].
#define GBK 64
__global__ __launch_bounds__(256) void k_gemm_mfma(const float* __restrict__ A,
                                                   const unsigned short* __restrict__ B,
                                                   const float* __restrict__ v1p,
                                                   const float* __restrict__ t1,
                                                   float* __restrict__ C,
                                                   float* __restrict__ vpart,
                                                   float* __restrict__ tpart) {
    const int N = D, K = H;
    __shared__ __align__(16) unsigned short As[128 * GBK];
    __shared__ __align__(16) unsigned short Bs[128 * GBK];
    __shared__ float vt[2048], tt[2048];
    int b = blockIdx.x;
    int u = b & 7, v = b >> 3;
    int z = u >> 2;
    int y = (u & 3) * 8 + (v >> 3);
    int xb = v & 7;
    int tid = threadIdx.x;
    int wave = tid >> 6, lane = tid & 63;
    int bm = y * 128, bn = xb * 128;
    int kbeg = z * (K / 2);
    float* Cz = C + (size_t)z * ((size_t)H * D);
    int wm = (wave >> 1) * 64, wn = (wave & 1) * 64;

    int srow = lane >> 3, sc = lane & 7, scp = sc ^ srow;   // B staging geometry
    int r15 = lane & 15, quad = lane >> 4, key = r15 & 7;   // read-side swizzle
    int rowg = tid >> 3, ch = tid & 7;                      // A staging geometry
    int aswz = ch ^ (rowg & 7);

    for (int idx = tid; idx < 512; idx += 256) {
        *(float4*)&vt[idx * 4] = *(const float4*)&v1p[kbeg + idx * 4];
        *(float4*)&tt[idx * 4] = *(const float4*)&t1[kbeg + idx * 4];
    }
    __syncthreads();

    f32x4 acc[4][4];
#pragma unroll
    for (int p = 0; p < 4; ++p)
#pragma unroll
        for (int q = 0; q < 4; ++q) acc[p][q] = (f32x4){0.f, 0.f, 0.f, 0.f};
    float sv[4] = {0.f, 0.f, 0.f, 0.f}, st[4] = {0.f, 0.f, 0.f, 0.f};

    for (int s = 0; s < (K / 2) / GBK; ++s) {
        int k0 = kbeg + s * GBK;
#pragma unroll
        for (int g = 0; g < 4; ++g) {
            int row = wave * 32 + g * 8;
            gl_lds16(&B[(size_t)(bn + row + srow) * K + k0 + scp * 8], &Bs[row * GBK]);
        }
        bool dodot = ((s & 7) == xb);
#pragma unroll
        for (int g = 0; g < 4; ++g) {
            int row = g * 32 + rowg;
            const float* ap = &A[(size_t)(bm + row) * K + k0 + ch * 8];
            float4 a0 = *(const float4*)ap;
            float4 a1v = *(const float4*)(ap + 4);
            if (dodot) {
                const float* vp = &vt[s * 64 + ch * 8];
                const float* tp = &tt[s * 64 + ch * 8];
                float4 v0 = *(const float4*)vp, v1 = *(const float4*)(vp + 4);
                float4 t0 = *(const float4*)tp, t1v = *(const float4*)(tp + 4);
                sv[g] += a0.x * v0.x + a0.y * v0.y + a0.z * v0.z + a0.w * v0.w
                       + a1v.x * v1.x + a1v.y * v1.y + a1v.z * v1.z + a1v.w * v1.w;
                st[g] += a0.x * t0.x + a0.y * t0.y + a0.z * t0.z + a0.w * t0.w
                       + a1v.x * t1v.x + a1v.y * t1v.y + a1v.z * t1v.z + a1v.w * t1v.w;
            }
            uint4 hh;
            hh.x = f2bf2_fast(a0.x, a0.y);
            hh.y = f2bf2_fast(a0.z, a0.w);
            hh.z = f2bf2_fast(a1v.x, a1v.y);
            hh.w = f2bf2_fast(a1v.z, a1v.w);
            *(uint4*)&As[row * GBK + aswz * 8] = hh;
        }
        __syncthreads();
#pragma unroll
        for (int kk = 0; kk < 2; ++kk) {
            short8 af[4], bf[4];
#pragma unroll
            for (int mt = 0; mt < 4; ++mt)
                af[mt] = *(const short8*)&As[(wm + mt * 16 + r15) * GBK + (((kk * 4 + quad) ^ key)) * 8];
#pragma unroll
            for (int nt = 0; nt < 4; ++nt)
                bf[nt] = *(const short8*)&Bs[(wn + nt * 16 + r15) * GBK + (((kk * 4 + quad) ^ key)) * 8];
#pragma unroll
            for (int mt = 0; mt < 4; ++mt)
#pragma unroll
                for (int nt = 0; nt < 4; ++nt)
                    acc[mt][nt] = __builtin_amdgcn_mfma_f32_16x16x32_bf16(af[mt], bf[nt], acc[mt][nt], 0, 0, 0);
        }
        __syncthreads();
    }

    // epilogue: C row = quad*4+reg, col = lane&15
#pragma unroll
    for (int mt = 0; mt < 4; ++mt) {
        int gr = bm + wm + mt * 16 + quad * 4;
#pragma unroll
        for (int nt = 0; nt < 4; ++nt) {
            int gc = bn + wn + nt * 16 + r15;
            Cz[(size_t)(gr + 0) * N + gc] = acc[mt][nt][0];
            Cz[(size_t)(gr + 1) * N + gc] = acc[mt][nt][1];
            Cz[(size_t)(gr + 2) * N + gc] = acc[mt][nt][2];
            Cz[(size_t)(gr + 3) * N + gc] = acc[mt][nt][3];
        }
    }

    // dot partials: reduce across the 8 lanes sharing a row, store race-free
#pragma unroll
    for (int g = 0; g < 4; ++g) {
        float a = sv[g], bb = st[g];
        a += __shfl_xor(a, 1, 64); a += __shfl_xor(a, 2, 64); a += __shfl_xor(a, 4, 64);
        bb += __shfl_xor(bb, 1, 64); bb += __shfl_xor(bb, 2, 64); bb += __shfl_xor(bb, 4, 64);
        if (ch == 0) {
            int i = bm + g * 32 + rowg;
            vpart[(size_t)(z * 8 + xb) * H + i] = a;
            tpart[(size_t)(z * 8 + xb) * H + i] = bb;
        }
    }
}

// wave-per-row: v2 = sum vpart + b2 ; t2col = sum tpart ; r2 = rowsum|e1+e2|+|t2col|
// ReLU-2 params ; fused w3s[i][o] = W3[o][i]*a2[i]
__global__ __launch_bounds__(256) void k_relu2(const float* __restrict__ e1, const float* __restrict__ e2,
                                               const float* __restrict__ vpart, const float* __restrict__ tpart,
                                               const float* __restrict__ b2, const float* __restrict__ W3,
                                               float* __restrict__ v2p, float* __restrict__ a2,
                                               float* __restrict__ t2, float* __restrict__ t2col,
                                               float* __restrict__ w3s) {
    int wid = threadIdx.x >> 6, lane = threadIdx.x & 63;
    int i = blockIdx.x * 4 + wid;
    float s = 0.f;
#pragma unroll
    for (int it = 0; it < 4; ++it) {
        int j = it * 256 + lane * 4;
        float4 a = *(const float4*)&e1[(size_t)i * D + j];
        float4 b = *(const float4*)&e2[(size_t)i * D + j];
        s += fabsf(a.x + b.x) + fabsf(a.y + b.y) + fabsf(a.z + b.z) + fabsf(a.w + b.w);
    }
    float ve = (lane < 16) ? vpart[(size_t)lane * H + i] : 0.f;
    float te = (lane < 16) ? tpart[(size_t)lane * H + i] : 0.f;
#pragma unroll
    for (int m = 1; m <= 32; m <<= 1) {
        s += __shfl_xor(s, m, 64);
        ve += __shfl_xor(ve, m, 64);
        te += __shfl_xor(te, m, 64);
    }
    float vo, ao, to;
    relu_params(ve + b2[i], s + fabsf(te), vo, ao, to);
    if (lane == 0) { v2p[i] = vo; a2[i] = ao; t2[i] = to; t2col[i] = te; }
    if (lane < O) w3s[(size_t)i * O + lane] = W3[(size_t)lane * H + i] * ao;
}

// pbuf[o][ib][j] = sum over 128-row i-slice ib of w3s[i][o] * (e1+e2)[i][j]
__global__ __launch_bounds__(256) void k_eps3a(const float* __restrict__ e1, const float* __restrict__ e2,
                                               const float* __restrict__ w3s,
                                               float* __restrict__ pbuf) {
    int jb = blockIdx.x, ib = blockIdx.y;      // 16 x 32
    int jj = threadIdx.x & 15, s = threadIdx.x >> 4;
    int j = jb * 64 + jj * 4;
    int i0 = ib * 128 + s * 8;
    float acc[4][O];
#pragma unroll
    for (int c = 0; c < 4; ++c)
#pragma unroll
        for (int o = 0; o < O; ++o) acc[c][o] = 0.f;
    for (int ii = 0; ii < 8; ++ii) {
        int i = i0 + ii;
        float4 a = *(const float4*)&e1[(size_t)i * D + j];
        float4 b = *(const float4*)&e2[(size_t)i * D + j];
        float e0 = a.x + b.x, ee1 = a.y + b.y, ee2 = a.z + b.z, ee3 = a.w + b.w;
        const float* w = &w3s[(size_t)i * O];
#pragma unroll
        for (int o = 0; o < O; ++o) {
            float wo = w[o];
            acc[0][o] += wo * e0; acc[1][o] += wo * ee1;
            acc[2][o] += wo * ee2; acc[3][o] += wo * ee3;
        }
    }
    __shared__ float sm[16][64][O];  // 40 KB
#pragma unroll
    for (int c = 0; c < 4; ++c)
#pragma unroll
        for (int o = 0; o < O; ++o) sm[s][jj * 4 + c][o] = acc[c][o];
    __syncthreads();
    for (int idx = threadIdx.x; idx < 64 * O; idx += 256) {
        int col = idx / O, o = idx % O;
        float t = 0.f;
#pragma unroll
        for (int ss = 0; ss < 16; ++ss) t += sm[ss][col][o];
        pbuf[((size_t)o * 32 + ib) * D + jb * 64 + col] = t;
    }
}

// fused eps3b + final: r3[o] = sum_j |sum_ib pbuf[o][ib][j]| ; dots ; output
__global__ __launch_bounds__(256) void k_final(const float* __restrict__ W3, const float* __restrict__ b3,
                                               const float* __restrict__ v2p, const float* __restrict__ a2,
                                               const float* __restrict__ t2col, const float* __restrict__ t2,
                                               const float* __restrict__ pbuf, float* __restrict__ out) {
    int o = blockIdx.x, tid = threadIdx.x;
    float s3 = 0.f;
    for (int j = tid; j < D; j += 256) {
        float t = 0.f;
#pragma unroll
        for (int ib = 0; ib < 32; ++ib) t += pbuf[((size_t)o * 32 + ib) * D + j];
        s3 += fabsf(t);
    }
    const float* row = W3 + (size_t)o * H;
    float sv = 0.f, s1 = 0.f, s2 = 0.f;
    for (int i = tid; i < H; i += 256) {
        float w = row[i];
        sv += w * v2p[i];
        s1 += w * a2[i] * t2col[i];
        s2 += w * t2[i];
    }
    __shared__ float ra[256], rb[256], rc[256], rd[256];
    ra[tid] = sv; rb[tid] = s1; rc[tid] = s2; rd[tid] = s3;
    __syncthreads();
    for (int off = 128; off; off >>= 1) {
        if (tid < off) {
            ra[tid] += ra[tid + off]; rb[tid] += rb[tid + off];
            rc[tid] += rc[tid + off]; rd[tid] += rd[tid + off];
        }
        __syncthreads();
    }
    if (tid == 0) {
        float v3 = ra[0] + b3[o];
        float rr = rd[0] + fabsf(rb[0]) + fabsf(rc[0]);
        out[o] = v3 + rr;       // u
        out[O + o] = v3 - rr;   // l
    }
}

// ---------------------------------------------------------------------------
extern "C" void kernel_launch(void* const* d_in, const int* in_sizes, int n_in,
                              void* d_out, int out_size, void* d_ws, size_t ws_size,
                              hipStream_t stream) {
    const float* x  = (const float*)d_in[0];
    const float* W1 = (const float*)d_in[1];
    const float* b1 = (const float*)d_in[2];
    const float* W2 = (const float*)d_in[3];
    const float* b2 = (const float*)d_in[4];
    const float* W3 = (const float*)d_in[5];
    const float* b3 = (const float*)d_in[6];
    float* out = (float*)d_out;

    float* p = (float*)d_ws;
    float* v1p    = p; p += H;
    float* a1     = p; p += H;
    float* t1     = p; p += H;
    float* t2col  = p; p += H;
    float* v2p    = p; p += H;
    float* a2     = p; p += H;
    float* t2     = p; p += H;
    float* w3s    = p; p += H * O + 8;
    float* vpart  = p; p += 16 * H;
    float* tpart  = p; p += 16 * H;
    float* pbuf   = p; p += 32 * O * D;                       // 1.25 MB
    float* eps2   = p; p += (size_t)2 * H * D;                // 2 x 16 MB fp32 (split-K partials)
    unsigned short* W1sT = (unsigned short*)p;                // 8 MB bf16
    float* eps2b = eps2 + (size_t)H * D;

    k_layer1<<<H / 4, 256, 0, stream>>>(W1, b1, x, v1p, a1, t1);
    k_scaleT<<<dim3(D / 32, H / 32), 256, 0, stream>>>(W1, a1, x, W1sT);
    k_gemm_mfma<<<512, 256, 0, stream>>>(W2, W1sT, v1p, t1, eps2, vpart, tpart);
    k_relu2<<<H / 4, 256, 0, stream>>>(eps2, eps2b, vpart, tpart, b2, W3, v2p, a2, t2, t2col, w3s);
    k_eps3a<<<dim3(D / 64, 32), 256, 0, stream>>>(eps2, eps2b, w3s, pbuf);
    k_final<<<O, 256, 0, stream>>>(W3, b3, v2p, a2, t2col, t2, pbuf, out);
}

// Round 7
// 206.951 us; speedup vs baseline: 1.1117x; 1.1117x over previous
//
#include <hip/hip_runtime.h>
#include <math.h>

#define ZEPS  0.01f
#define ZMEAN 0.1307f
#define ZSIGMA 0.3081f

constexpr int D = 1024, H = 4096, O = 10;

using short8 = __attribute__((ext_vector_type(8))) short;
using f32x4  = __attribute__((ext_vector_type(4))) float;
typedef unsigned short ushort_t;

__device__ inline unsigned short f2bf(float x) {  // RNE fp32 -> bf16 bits
    unsigned int u = __float_as_uint(x);
    u += 0x7FFFu + ((u >> 16) & 1u);
    return (unsigned short)(u >> 16);
}
__device__ inline float bf2f(unsigned short h) {
    return __uint_as_float(((unsigned int)h) << 16);
}

// round-half-up fp32 pair -> packed bf16x2 (2 ops/elt)
__device__ inline unsigned int f2bf2_fast(float a, float b) {
    unsigned int ua = __float_as_uint(a) + 0x8000u;
    unsigned int ub = __float_as_uint(b) + 0x8000u;
    return (ua >> 16) | (ub & 0xFFFF0000u);
}

// async 16B/lane global->LDS (lds dest = base + lane*16, wave-uniform base)
__device__ inline void gl_lds16(const void* g, void* l) {
    __builtin_amdgcn_global_load_lds(
        (const __attribute__((address_space(1))) unsigned int*)g,
        (__attribute__((address_space(3))) unsigned int*)l, 16, 0, 0);
}

__device__ inline float zval(float xv) {
    float up = fminf(xv + ZEPS, 1.f);
    float lo = fmaxf(xv - ZEPS, 0.f);
    return (up + lo - ZMEAN) / ZSIGMA;
}
__device__ inline float zdia(float xv) {
    return fminf(xv + ZEPS, 1.f) / ZSIGMA;
}

// ---------------------------------------------------------------------------
__device__ inline void relu_params(float v, float r, float& vout, float& aout, float& tout) {
    float u = v + r, l = v - r;
    float denom = u - l;
    float slope = u / (denom == 0.f ? 1.f : denom);
    float term = (1.f - slope) * u * 0.5f;
    bool dead = (u <= 0.f);
    bool crossing = (u > 0.f) && (l < 0.f);
    vout = dead ? 0.f : (crossing ? (slope * v + term) : v);
    aout = dead ? 0.f : (crossing ? slope : 1.f);
    tout = (!dead && crossing) ? term : 0.f;
}

// ---------------------------------------------------------------------------
// wave-per-row: v1 = W1@values+b1 ; r1 = |W1| @ d ; ReLU-1 params
__global__ __launch_bounds__(256) void k_layer1(const float* __restrict__ W1, const float* __restrict__ b1,
                                                const float* __restrict__ x,
                                                float* __restrict__ v1p, float* __restrict__ a1,
                                                float* __restrict__ t1) {
    int wid = threadIdx.x >> 6, lane = threadIdx.x & 63;
    int i = blockIdx.x * 4 + wid;
    const float* row = W1 + (size_t)i * D;
    float sv = 0.f, sr = 0.f;
#pragma unroll
    for (int it = 0; it < 4; ++it) {
        int j = it * 256 + lane * 4;
        float4 w = *(const float4*)&row[j];
        float4 xx = *(const float4*)&x[j];
        sv += w.x * zval(xx.x) + w.y * zval(xx.y) + w.z * zval(xx.z) + w.w * zval(xx.w);
        sr += fabsf(w.x) * zdia(xx.x) + fabsf(w.y) * zdia(xx.y) +
              fabsf(w.z) * zdia(xx.z) + fabsf(w.w) * zdia(xx.w);
    }
#pragma unroll
    for (int m = 1; m <= 32; m <<= 1) {
        sv += __shfl_xor(sv, m, 64);
        sr += __shfl_xor(sr, m, 64);
    }
    if (lane == 0) {
        float vo, ao, to;
        relu_params(sv + b1[i], sr, vo, ao, to);
        v1p[i] = vo; a1[i] = ao; t1[i] = to;
    }
}

// W1sT[j][k] = bf16( a1[k] * W1[k][j] * d[j] )  — transposed, k-contiguous
__global__ __launch_bounds__(256) void k_scaleT(const float* __restrict__ W1, const float* __restrict__ a1,
                                                const float* __restrict__ x,
                                                ushort_t* __restrict__ W1sT) {
    __shared__ float tile[32][33];
    int j0 = blockIdx.x * 32, k0 = blockIdx.y * 32;
    int r = threadIdx.x >> 3;
    int c = (threadIdx.x & 7) * 4;
    float4 w = *(const float4*)&W1[(size_t)(k0 + r) * D + j0 + c];
    float4 xx = *(const float4*)&x[j0 + c];
    float a = a1[k0 + r];
    tile[r][c + 0] = a * w.x * zdia(xx.x);
    tile[r][c + 1] = a * w.y * zdia(xx.y);
    tile[r][c + 2] = a * w.z * zdia(xx.z);
    tile[r][c + 3] = a * w.w * zdia(xx.w);
    __syncthreads();
    ushort4 o;
    o.x = f2bf(tile[c + 0][r]);
    o.y = f2bf(tile[c + 1][r]);
    o.z = f2bf(tile[c + 2][r]);
    o.w = f2bf(tile[c + 3][r]);
    *(ushort4*)&W1sT[(size_t)(j0 + r) * H + k0 + c] = o;
}

// ---------------------------------------------------------------------------
// eps2(bf16) = bf16(W2) @ W1sT^T, split-K=2, XCD remap. Software-pipelined:
// double-buffered As/Bs, 1 barrier/iter. A staged fp32->regs (prefetched one
// step ahead, latency hidden under MFMA) -> cvt -> swizzled ds_write.
// v2/t2col partial dots from the fp32 A regs on steps (s&7)==xb.
#define GBK 64
__global__ __launch_bounds__(256) void k_gemm_mfma(const float* __restrict__ A,
                                                   const ushort_t* __restrict__ B,
                                                   const float* __restrict__ v1p,
                                                   const float* __restrict__ t1,
                                                   ushort_t* __restrict__ C,
                                                   float* __restrict__ vpart,
                                                   float* __restrict__ tpart) {
    const int N = D, K = H;
    __shared__ __align__(16) ushort_t As[2][128 * GBK];   // 2 x 16 KB
    __shared__ __align__(16) ushort_t Bs[2][128 * GBK];   // 2 x 16 KB
    __shared__ float vt[2048], tt[2048];                  // 16 KB
    int b = blockIdx.x;
    int u = b & 7, v = b >> 3;
    int z = u >> 2;
    int y = (u & 3) * 8 + (v >> 3);
    int xb = v & 7;
    int tid = threadIdx.x;
    int wave = tid >> 6, lane = tid & 63;
    int bm = y * 128, bn = xb * 128;
    int kbeg = z * (K / 2);
    ushort_t* Cz = C + (size_t)z * ((size_t)H * D);
    int wm = (wave >> 1) * 64, wn = (wave & 1) * 64;

    int srow = lane >> 3, sc = lane & 7, scp = sc ^ srow;   // B staging geometry
    int r15 = lane & 15, quad = lane >> 4, key = r15 & 7;   // read-side swizzle
    int rowg = tid >> 3, ch = tid & 7;                      // A staging geometry
    int aswz = ch ^ (rowg & 7);

    const int S = (K / 2) / GBK;  // 32

    float4 pa[4][2];
    float sv[4] = {0.f, 0.f, 0.f, 0.f}, st[4] = {0.f, 0.f, 0.f, 0.f};

    auto issueA = [&](int s) {
#pragma unroll
        for (int g = 0; g < 4; ++g) {
            const float* ap = &A[(size_t)(bm + g * 32 + rowg) * K + kbeg + s * GBK + ch * 8];
            pa[g][0] = *(const float4*)ap;
            pa[g][1] = *(const float4*)(ap + 4);
        }
    };
    auto issueB = [&](int s, int buf) {
#pragma unroll
        for (int g = 0; g < 2; ++g) {
            int row = wave * 32 + g * 16;  // 2 gl_lds x (8 rows each) per 32-row wave slice? no: 16B*64 lanes = 8 rows
            // each gl_lds covers 8 rows; need 4 per wave for 32 rows
            (void)row;
        }
#pragma unroll
        for (int g = 0; g < 4; ++g) {
            int row = wave * 32 + g * 8;
            gl_lds16(&B[(size_t)(bn + row + srow) * K + kbeg + s * GBK + scp * 8], &Bs[buf][row * GBK]);
        }
    };
    auto cvtwrite = [&](int s, int buf) {
        if ((s & 7) == xb) {
            const float* vp = &vt[s * 64 + ch * 8];
            const float* tp = &tt[s * 64 + ch * 8];
            float4 v0 = *(const float4*)vp, v1 = *(const float4*)(vp + 4);
            float4 t0 = *(const float4*)tp, t1v = *(const float4*)(tp + 4);
#pragma unroll
            for (int g = 0; g < 4; ++g) {
                sv[g] += pa[g][0].x * v0.x + pa[g][0].y * v0.y + pa[g][0].z * v0.z + pa[g][0].w * v0.w
                       + pa[g][1].x * v1.x + pa[g][1].y * v1.y + pa[g][1].z * v1.z + pa[g][1].w * v1.w;
                st[g] += pa[g][0].x * t0.x + pa[g][0].y * t0.y + pa[g][0].z * t0.z + pa[g][0].w * t0.w
                       + pa[g][1].x * t1v.x + pa[g][1].y * t1v.y + pa[g][1].z * t1v.z + pa[g][1].w * t1v.w;
            }
        }
#pragma unroll
        for (int g = 0; g < 4; ++g) {
            uint4 hh;
            hh.x = f2bf2_fast(pa[g][0].x, pa[g][0].y);
            hh.y = f2bf2_fast(pa[g][0].z, pa[g][0].w);
            hh.z = f2bf2_fast(pa[g][1].x, pa[g][1].y);
            hh.w = f2bf2_fast(pa[g][1].z, pa[g][1].w);
            *(uint4*)&As[buf][(g * 32 + rowg) * GBK + aswz * 8] = hh;
        }
    };

    f32x4 acc[4][4];
#pragma unroll
    for (int p = 0; p < 4; ++p)
#pragma unroll
        for (int q = 0; q < 4; ++q) acc[p][q] = (f32x4){0.f, 0.f, 0.f, 0.f};

    // prologue
    issueA(0);
    issueB(0, 0);
    for (int idx = tid; idx < 512; idx += 256) {
        *(float4*)&vt[idx * 4] = *(const float4*)&v1p[kbeg + idx * 4];
        *(float4*)&tt[idx * 4] = *(const float4*)&t1[kbeg + idx * 4];
    }
    __syncthreads();          // vt/tt visible (also drains B(0) DMA — prologue only)
    cvtwrite(0, 0);
    __syncthreads();

    for (int s = 0; s < S; ++s) {
        int buf = s & 1, nbuf = buf ^ 1;
        if (s + 1 < S) {
            issueA(s + 1);
            issueB(s + 1, nbuf);
        }
#pragma unroll
        for (int kk = 0; kk < 2; ++kk) {
            short8 af[4], bf[4];
#pragma unroll
            for (int mt = 0; mt < 4; ++mt)
                af[mt] = *(const short8*)&As[buf][(wm + mt * 16 + r15) * GBK + (((kk * 4 + quad) ^ key)) * 8];
#pragma unroll
            for (int nt = 0; nt < 4; ++nt)
                bf[nt] = *(const short8*)&Bs[buf][(wn + nt * 16 + r15) * GBK + (((kk * 4 + quad) ^ key)) * 8];
#pragma unroll
            for (int mt = 0; mt < 4; ++mt)
#pragma unroll
                for (int nt = 0; nt < 4; ++nt)
                    acc[mt][nt] = __builtin_amdgcn_mfma_f32_16x16x32_bf16(af[mt], bf[nt], acc[mt][nt], 0, 0, 0);
        }
        if (s + 1 < S) cvtwrite(s + 1, nbuf);
        __syncthreads();
    }

    // epilogue: C row = quad*4+reg, col = lane&15; bf16 store
#pragma unroll
    for (int mt = 0; mt < 4; ++mt) {
        int gr = bm + wm + mt * 16 + quad * 4;
#pragma unroll
        for (int nt = 0; nt < 4; ++nt) {
            int gc = bn + wn + nt * 16 + r15;
            Cz[(size_t)(gr + 0) * N + gc] = f2bf(acc[mt][nt][0]);
            Cz[(size_t)(gr + 1) * N + gc] = f2bf(acc[mt][nt][1]);
            Cz[(size_t)(gr + 2) * N + gc] = f2bf(acc[mt][nt][2]);
            Cz[(size_t)(gr + 3) * N + gc] = f2bf(acc[mt][nt][3]);
        }
    }

    // dot partials: reduce across the 8 lanes sharing a row, store race-free
#pragma unroll
    for (int g = 0; g < 4; ++g) {
        float a = sv[g], bb = st[g];
        a += __shfl_xor(a, 1, 64); a += __shfl_xor(a, 2, 64); a += __shfl_xor(a, 4, 64);
        bb += __shfl_xor(bb, 1, 64); bb += __shfl_xor(bb, 2, 64); bb += __shfl_xor(bb, 4, 64);
        if (ch == 0) {
            int i = bm + g * 32 + rowg;
            vpart[(size_t)(z * 8 + xb) * H + i] = a;
            tpart[(size_t)(z * 8 + xb) * H + i] = bb;
        }
    }
}

// wave-per-row: v2 = sum vpart + b2 ; t2col = sum tpart ; r2 = rowsum|e1+e2|+|t2col|
// ReLU-2 params ; fused w3s[i][o] = W3[o][i]*a2[i]   (e1,e2 are bf16)
__global__ __launch_bounds__(256) void k_relu2(const ushort_t* __restrict__ e1, const ushort_t* __restrict__ e2,
                                               const float* __restrict__ vpart, const float* __restrict__ tpart,
                                               const float* __restrict__ b2, const float* __restrict__ W3,
                                               float* __restrict__ v2p, float* __restrict__ a2,
                                               float* __restrict__ t2, float* __restrict__ t2col,
                                               float* __restrict__ w3s) {
    int wid = threadIdx.x >> 6, lane = threadIdx.x & 63;
    int i = blockIdx.x * 4 + wid;
    float s = 0.f;
#pragma unroll
    for (int it = 0; it < 2; ++it) {
        int j = lane * 8 + it * 512;
        ushort4 a0 = *(const ushort4*)&e1[(size_t)i * D + j];
        ushort4 a1v = *(const ushort4*)&e1[(size_t)i * D + j + 4];
        ushort4 b0 = *(const ushort4*)&e2[(size_t)i * D + j];
        ushort4 b1v = *(const ushort4*)&e2[(size_t)i * D + j + 4];
        s += fabsf(bf2f(a0.x) + bf2f(b0.x)) + fabsf(bf2f(a0.y) + bf2f(b0.y))
           + fabsf(bf2f(a0.z) + bf2f(b0.z)) + fabsf(bf2f(a0.w) + bf2f(b0.w))
           + fabsf(bf2f(a1v.x) + bf2f(b1v.x)) + fabsf(bf2f(a1v.y) + bf2f(b1v.y))
           + fabsf(bf2f(a1v.z) + bf2f(b1v.z)) + fabsf(bf2f(a1v.w) + bf2f(b1v.w));
    }
    float ve = (lane < 16) ? vpart[(size_t)lane * H + i] : 0.f;
    float te = (lane < 16) ? tpart[(size_t)lane * H + i] : 0.f;
#pragma unroll
    for (int m = 1; m <= 32; m <<= 1) {
        s += __shfl_xor(s, m, 64);
        ve += __shfl_xor(ve, m, 64);
        te += __shfl_xor(te, m, 64);
    }
    float vo, ao, to;
    relu_params(ve + b2[i], s + fabsf(te), vo, ao, to);
    if (lane == 0) { v2p[i] = vo; a2[i] = ao; t2[i] = to; t2col[i] = te; }
    if (lane < O) w3s[(size_t)i * O + lane] = W3[(size_t)lane * H + i] * ao;
}

// pbuf[o][ib][j] = sum over 128-row i-slice ib of w3s[i][o] * (e1+e2)[i][j]  (bf16 e)
__global__ __launch_bounds__(256) void k_eps3a(const ushort_t* __restrict__ e1, const ushort_t* __restrict__ e2,
                                               const float* __restrict__ w3s,
                                               float* __restrict__ pbuf) {
    int jb = blockIdx.x, ib = blockIdx.y;      // 16 x 32
    int jj = threadIdx.x & 15, s = threadIdx.x >> 4;
    int j = jb * 64 + jj * 4;
    int i0 = ib * 128 + s * 8;
    float acc[4][O];
#pragma unroll
    for (int c = 0; c < 4; ++c)
#pragma unroll
        for (int o = 0; o < O; ++o) acc[c][o] = 0.f;
    for (int ii = 0; ii < 8; ++ii) {
        int i = i0 + ii;
        ushort4 a = *(const ushort4*)&e1[(size_t)i * D + j];
        ushort4 b = *(const ushort4*)&e2[(size_t)i * D + j];
        float e0 = bf2f(a.x) + bf2f(b.x), ee1 = bf2f(a.y) + bf2f(b.y);
        float ee2 = bf2f(a.z) + bf2f(b.z), ee3 = bf2f(a.w) + bf2f(b.w);
        const float* w = &w3s[(size_t)i * O];
#pragma unroll
        for (int o = 0; o < O; ++o) {
            float wo = w[o];
            acc[0][o] += wo * e0; acc[1][o] += wo * ee1;
            acc[2][o] += wo * ee2; acc[3][o] += wo * ee3;
        }
    }
    __shared__ float sm[16][64][O];  // 40 KB
#pragma unroll
    for (int c = 0; c < 4; ++c)
#pragma unroll
        for (int o = 0; o < O; ++o) sm[s][jj * 4 + c][o] = acc[c][o];
    __syncthreads();
    for (int idx = threadIdx.x; idx < 64 * O; idx += 256) {
        int col = idx / O, o = idx % O;
        float t = 0.f;
#pragma unroll
        for (int ss = 0; ss < 16; ++ss) t += sm[ss][col][o];
        pbuf[((size_t)o * 32 + ib) * D + jb * 64 + col] = t;
    }
}

// fused eps3b + final
__global__ __launch_bounds__(256) void k_final(const float* __restrict__ W3, const float* __restrict__ b3,
                                               const float* __restrict__ v2p, const float* __restrict__ a2,
                                               const float* __restrict__ t2col, const float* __restrict__ t2,
                                               const float* __restrict__ pbuf, float* __restrict__ out) {
    int o = blockIdx.x, tid = threadIdx.x;
    float s3 = 0.f;
    for (int j = tid; j < D; j += 256) {
        float t = 0.f;
#pragma unroll
        for (int ib = 0; ib < 32; ++ib) t += pbuf[((size_t)o * 32 + ib) * D + j];
        s3 += fabsf(t);
    }
    const float* row = W3 + (size_t)o * H;
    float sv = 0.f, s1 = 0.f, s2 = 0.f;
    for (int i = tid; i < H; i += 256) {
        float w = row[i];
        sv += w * v2p[i];
        s1 += w * a2[i] * t2col[i];
        s2 += w * t2[i];
    }
    __shared__ float ra[256], rb[256], rc[256], rd[256];
    ra[tid] = sv; rb[tid] = s1; rc[tid] = s2; rd[tid] = s3;
    __syncthreads();
    for (int off = 128; off; off >>= 1) {
        if (tid < off) {
            ra[tid] += ra[tid + off]; rb[tid] += rb[tid + off];
            rc[tid] += rc[tid + off]; rd[tid] += rd[tid + off];
        }
        __syncthreads();
    }
    if (tid == 0) {
        float v3 = ra[0] + b3[o];
        float rr = rd[0] + fabsf(rb[0]) + fabsf(rc[0]);
        out[o] = v3 + rr;       // u
        out[O + o] = v3 - rr;   // l
    }
}

// ---------------------------------------------------------------------------
extern "C" void kernel_launch(void* const* d_in, const int* in_sizes, int n_in,
                              void* d_out, int out_size, void* d_ws, size_t ws_size,
                              hipStream_t stream) {
    const float* x  = (const float*)d_in[0];
    const float* W1 = (const float*)d_in[1];
    const float* b1 = (const float*)d_in[2];
    const float* W2 = (const float*)d_in[3];
    const float* b2 = (const float*)d_in[4];
    const float* W3 = (const float*)d_in[5];
    const float* b3 = (const float*)d_in[6];
    float* out = (float*)d_out;

    float* p = (float*)d_ws;
    float* v1p    = p; p += H;
    float* a1     = p; p += H;
    float* t1     = p; p += H;
    float* t2col  = p; p += H;
    float* v2p    = p; p += H;
    float* a2     = p; p += H;
    float* t2     = p; p += H;
    float* w3s    = p; p += H * O + 8;
    float* vpart  = p; p += 16 * H;
    float* tpart  = p; p += 16 * H;
    float* pbuf   = p; p += 32 * O * D;                       // 1.25 MB
    ushort_t* eps2  = (ushort_t*)p;                           // 2 x 8 MB bf16 (split-K partials)
    ushort_t* W1sT  = eps2 + (size_t)2 * H * D;               // 8 MB bf16
    ushort_t* eps2b = eps2 + (size_t)H * D;

    k_layer1<<<H / 4, 256, 0, stream>>>(W1, b1, x, v1p, a1, t1);
    k_scaleT<<<dim3(D / 32, H / 32), 256, 0, stream>>>(W1, a1, x, W1sT);
    k_gemm_mfma<<<512, 256, 0, stream>>>(W2, W1sT, v1p, t1, eps2, vpart, tpart);
    k_relu2<<<H / 4, 256, 0, stream>>>(eps2, eps2b, vpart, tpart, b2, W3, v2p, a2, t2, t2col, w3s);
    k_eps3a<<<dim3(D / 64, 32), 256, 0, stream>>>(eps2, eps2b, w3s, pbuf);
    k_final<<<O, 256, 0, stream>>>(W3, b3, v2p, a2, t2col, t2, pbuf, out);
}